// Round 14
// baseline (200.244 us; speedup 1.0000x reference)
//
#include <hip/hip_runtime.h>
#include <math.h>

#define BATCH  32768
#define D      128
#define K      6400
#define KC     64
#define ROWS_PER_BLOCK 128
#define CHUNK_C 128
#define NCHUNKS 50                    // 50 * 128 = 6400 centers, full K per block

typedef _Float16 half8 __attribute__((ext_vector_type(8)));
typedef float    floatx16 __attribute__((ext_vector_type(16)));

typedef __attribute__((address_space(3))) unsigned       lds_uint;
typedef __attribute__((address_space(1))) const unsigned glb_uint;

__device__ __forceinline__ void async_lds16(const void* g, void* l) {
    __builtin_amdgcn_global_load_lds((glb_uint*)g, (lds_uint*)l, 16, 0, 0);
}

// ---- pack centers to fp16 (chunk-major) + c2n = -0.5*||c||^2 ----
// 16B unit n = ch*2048 + kb*128 + cw holds center (ch*128+cw), k in [kb*8, kb*8+8).
// (identical layout to the verified R4/R9/R11 pack)
__global__ __launch_bounds__(256) void pack_kernel(const float* __restrict__ centers,
                                                   _Float16* __restrict__ wh,
                                                   float* __restrict__ c2n) {
    int tid = blockIdx.x * 256 + threadIdx.x;   // 0 .. K*16-1
    int ch = tid >> 11;
    int kb = (tid >> 7) & 15;
    int cw = tid & 127;
    int center = ch * CHUNK_C + cw;
    const float* src = centers + (size_t)center * D + kb * 8;
    float4 a = *(const float4*)src;
    float4 b = *(const float4*)(src + 4);
    float f[8] = {a.x, a.y, a.z, a.w, b.x, b.y, b.z, b.w};
    half8 h;
#pragma unroll
    for (int j = 0; j < 8; ++j) h[j] = (_Float16)f[j];
    *(half8*)(wh + (size_t)tid * 8) = h;

    if (blockIdx.x < K / KC) {
        int c_local = threadIdx.x >> 2, part = threadIdx.x & 3;
        int c = blockIdx.x * 64 + c_local;
        const float4* p = (const float4*)(centers + (size_t)c * D + part * 32);
        float s = 0.f;
#pragma unroll
        for (int i = 0; i < 8; ++i) {
            float4 v = p[i];
            s = fmaf(v.x, v.x, s); s = fmaf(v.y, v.y, s);
            s = fmaf(v.z, v.z, s); s = fmaf(v.w, v.w, s);
        }
        s += __shfl_xor(s, 1, 64);
        s += __shfl_xor(s, 2, 64);
        if (part == 0) c2n[c] = -0.5f * s;
    }
}

// ---- single-pass distance kernel: 128 rows/block, full K, 32x32x16 MFMA ----
// v14 = R11 geometry (256 blocks x 1024 threads, 16 waves = 4rq x 4cq, dbuf LDS,
// 1 barrier/chunk) with the MFMA shape switched 16x16x32 -> 32x32x16:
//   +13% MFMA pipe rate (2382 vs 2075 TF ubench), 8 insts/wave/chunk vs 16,
//   screening loses the ct pair-reduce (each lane holds ONE column: col=lane&31).
// A: row=lane&31, k=(lane>>5)*8+e (analog of the verified 16x16 mapping);
// B: col=lane&31, same k; C/D: col=lane&31, row=(reg&3)+8*(reg>>2)+4*(lane>>5)
// [HW-verified m74/m101]. Packed best-2 (epoch=ci in low 7 mantissa bits),
// merge + exact fp32 refine + outputs identical to R11.
__global__ __launch_bounds__(1024, 4) void dist_kernel(
    const float* __restrict__ x, const float* __restrict__ centers,
    const _Float16* __restrict__ wh, const float* __restrict__ c2n,
    float* __restrict__ out) {
    __shared__ char lds[65536];   // two 32 KB chunk buffers; aliased in epilogue

    const int t   = threadIdx.x;
    const int w   = t >> 6;       // wave 0..15
    const int L   = t & 63;
    const int col = L & 31;       // center column within wave tile
    const int hi  = L >> 5;       // k-half selector (also +4 row offset in C)
    const int cq  = w & 3;        // center quarter of chunk (32 centers)
    const int rq  = w >> 2;       // row quarter 0..3 (32 rows each)
    const int gr0 = blockIdx.x * ROWS_PER_BLOCK;
    const int laneC = cq * 32 + col;   // lane's center column within chunk

    // ---- preload A fragments: row r = gr0 + rq*32 + col, k = ks*16 + hi*8 + e
    half8 Ah[8];
    {
        int r = gr0 + rq * 32 + col;
        const float* xr = x + (size_t)r * D + hi * 8;
#pragma unroll
        for (int ks = 0; ks < 8; ++ks) {
            float4 a = *(const float4*)(xr + ks * 16);
            float4 b = *(const float4*)(xr + ks * 16 + 4);
            float f[8] = {a.x, a.y, a.z, a.w, b.x, b.y, b.z, b.w};
            half8 h;
#pragma unroll
            for (int j = 0; j < 8; ++j) h[j] = (_Float16)f[j];
            Ah[ks] = h;
        }
    }

    // packed best-2 per slot reg = 0..15 (value | 7-bit epoch in low mantissa)
    float b1[16], b2[16];
#pragma unroll
    for (int k = 0; k < 16; ++k) { b1[k] = -1e30f; b2[k] = -1e30f; }

    const char* gh = (const char*)wh;

    // prologue: stage chunk 0 into buf0 (2 async16 per thread: 1024*2*16B = 32 KB)
#pragma unroll
    for (int i = 0; i < 2; ++i) {
        int seg = w * 2 + i;                           // wave-uniform, 0..31
        async_lds16(gh + seg * 1024 + L * 16, lds + seg * 1024);
    }

    // prologue: c2 for chunk 0 (one center column per lane)
    float c2vA = c2n[laneC], c2vB;
    __syncthreads();

    for (int ci = 0; ci < NCHUNKS; ++ci) {
        const char* cur = lds + (ci & 1) * 32768;
        // prefetch next chunk (no wait — lands during compute below)
        if (ci + 1 < NCHUNKS) {
            const char* gn = gh + (size_t)(ci + 1) * 32768;
            char* nxt = lds + ((ci + 1) & 1) * 32768;
#pragma unroll
            for (int i = 0; i < 2; ++i) {
                int seg = w * 2 + i;
                async_lds16(gn + seg * 1024 + L * 16, nxt + seg * 1024);
            }
            c2vB = c2n[(ci + 1) * CHUNK_C + laneC];
        }

        floatx16 acc;
#pragma unroll
        for (int r = 0; r < 16; ++r) acc[r] = c2vA;

        __builtin_amdgcn_s_setprio(1);
#pragma unroll
        for (int ks = 0; ks < 8; ++ks) {
            // B unit: kb = 2*ks + hi, center = laneC
            half8 Bf = *(const half8*)(cur + (((2 * ks + hi) << 7) + laneC) * 16);
            acc = __builtin_amdgcn_mfma_f32_32x32x16_f16(Ah[ks], Bf, acc, 0, 0, 0);
        }
        __builtin_amdgcn_s_setprio(0);

        // pack epoch (ci) into low 7 mantissa bits, packed best-2 insert
        const unsigned pk = (unsigned)ci;
#pragma unroll
        for (int reg = 0; reg < 16; ++reg) {
            float v = __uint_as_float((__float_as_uint(acc[reg]) & ~127u) | pk);
            b2[reg] = __builtin_amdgcn_fmed3f(b1[reg], b2[reg], v);  // exact 2nd-max
            b1[reg] = fmaxf(b1[reg], v);
        }

        c2vA = c2vB;

        __syncthreads();   // prefetch drained (free) + all waves done reading cur
    }

    int* candL = (int*)lds;       // [128 rows][8 candidates] — buffers dead now

    // decode epochs -> center indices, merge best-2 across the 32 columns
    // (butterfly m=1..16 stays within each 32-lane half; hi-half = rows +4)
#pragma unroll
    for (int reg = 0; reg < 16; ++reg) {
        unsigned u1 = __float_as_uint(b1[reg]), u2 = __float_as_uint(b2[reg]);
        int e1 = (int)(u1 & 127u), e2 = (int)(u2 & 127u);
        int p1 = e1 * CHUNK_C + laneC;
        int p2 = e2 * CHUNK_C + laneC;
        float v1 = b1[reg], v2 = b2[reg];
#pragma unroll
        for (int m = 1; m < 32; m <<= 1) {
            float o1 = __shfl_xor(v1, m, 64), o2 = __shfl_xor(v2, m, 64);
            int   q1 = __shfl_xor(p1, m, 64), q2 = __shfl_xor(p2, m, 64);
            bool firstMine = (v1 > o1) || (v1 == o1 && p1 < q1);
            float nv1 = firstMine ? v1 : o1;  int np1 = firstMine ? p1 : q1;
            float cb  = firstMine ? o1 : v1;  int cpi = firstMine ? q1 : p1;  // loser of firsts
            float ob  = firstMine ? v2 : o2;  int obi = firstMine ? p2 : q2;  // winner's own 2nd
            bool secOwn = (ob > cb) || (ob == cb && obi < cpi);
            v1 = nv1; p1 = np1;
            v2 = secOwn ? ob : cb;  p2 = secOwn ? obi : cpi;
        }
        if (col == 0) {
            // C/D row mapping: row = (reg&3) + 8*(reg>>2) + 4*hi  [m74/m101]
            int rloc = rq * 32 + (reg & 3) + 8 * (reg >> 2) + 4 * hi;
            candL[rloc * 8 + cq * 2 + 0] = p1;
            candL[rloc * 8 + cq * 2 + 1] = p2;
        }
    }
    __syncthreads();

    // exact fp32 refine: 8 candidates/row, 1 per thread (128 rows x 8 threads)
    // then write ALL outputs directly (quantized, cluster, min-dist, class)
    {
        int r = t >> 3, p = t & 7;
        int row = gr0 + r;
        int ix = candL[r * 8 + p];
        const float4* xr4 = (const float4*)(x + (size_t)row * D);
        const float4* c4  = (const float4*)(centers + (size_t)ix * D);
        float dot = 0.f, x2s = 0.f, c2 = 0.f;
#pragma unroll
        for (int d4 = 0; d4 < 32; ++d4) {
            float4 xv = xr4[d4], cv = c4[d4];
            dot = fmaf(xv.x, cv.x, dot); dot = fmaf(xv.y, cv.y, dot);
            dot = fmaf(xv.z, cv.z, dot); dot = fmaf(xv.w, cv.w, dot);
            x2s = fmaf(xv.x, xv.x, x2s); x2s = fmaf(xv.y, xv.y, x2s);
            x2s = fmaf(xv.z, xv.z, x2s); x2s = fmaf(xv.w, xv.w, x2s);
            c2  = fmaf(cv.x, cv.x, c2);  c2  = fmaf(cv.y, cv.y, c2);
            c2  = fmaf(cv.z, cv.z, c2);  c2  = fmaf(cv.w, cv.w, c2);
        }
        float sq = x2s + c2 - 2.f * dot;
        // butterfly min-reduce with lowest-index tie-break: all 8 lanes converge
#pragma unroll
        for (int m = 1; m < 8; m <<= 1) {
            float osq = __shfl_xor(sq, m, 64);
            int   oix = __shfl_xor(ix, m, 64);
            if (osq < sq || (osq == sq && oix < ix)) { sq = osq; ix = oix; }
        }

        float* out_clu = out + (size_t)BATCH * D;
        float* out_md  = out_clu + BATCH;
        float* out_cls = out_md + BATCH;
        if (p == 0) {
            out_md[row]  = sqrtf(fmaxf(sq, 0.f));
            out_clu[row] = (float)(ix & (KC - 1));
            out_cls[row] = (float)(ix >> 6);
        }

        // quantized = x + (c - x), elementwise in fp32 (matches reference exactly)
        const float4* cv4 = (const float4*)(centers + (size_t)ix * D) + p * 4;
        const float4* xv4 = (const float4*)(x + (size_t)row * D) + p * 4;
        float4* o4 = (float4*)(out + (size_t)row * D) + p * 4;
#pragma unroll
        for (int i = 0; i < 4; ++i) {
            float4 cv = cv4[i], xv = xv4[i];
            float4 o;
            o.x = xv.x + (cv.x - xv.x);
            o.y = xv.y + (cv.y - xv.y);
            o.z = xv.z + (cv.z - xv.z);
            o.w = xv.w + (cv.w - xv.w);
            o4[i] = o;
        }
    }
}

extern "C" void kernel_launch(void* const* d_in, const int* in_sizes, int n_in,
                              void* d_out, int out_size, void* d_ws, size_t ws_size,
                              hipStream_t stream) {
    const float* x       = (const float*)d_in[0];
    const float* centers = (const float*)d_in[1];
    // d_in[2] = labels (int64) — unused by the forward computation
    float* out = (float*)d_out;

    _Float16* wh  = (_Float16*)d_ws;                  // K*D halves, chunk-major
    float*    c2n = (float*)(wh + (size_t)K * D);     // K floats

    pack_kernel<<<(K * 16) / 256, 256, 0, stream>>>(centers, wh, c2n);
    dist_kernel<<<BATCH / ROWS_PER_BLOCK, 1024, 0, stream>>>(x, centers, wh, c2n, out);
}

// Round 15
// 172.571 us; speedup vs baseline: 1.1604x; 1.1604x over previous
//
#include <hip/hip_runtime.h>
#include <math.h>

#define BATCH  32768
#define D      128
#define K      6400
#define KC     64
#define ROWS_PER_BLOCK 128
#define CHUNK_C 128
#define NCHUNKS 50                    // 50 * 128 = 6400 centers, full K per block

typedef _Float16 half8 __attribute__((ext_vector_type(8)));
typedef float    floatx4 __attribute__((ext_vector_type(4)));

typedef __attribute__((address_space(3))) unsigned       lds_uint;
typedef __attribute__((address_space(1))) const unsigned glb_uint;

__device__ __forceinline__ void async_lds16(const void* g, void* l) {
    __builtin_amdgcn_global_load_lds((glb_uint*)g, (lds_uint*)l, 16, 0, 0);
}

// ---- pack centers to fp16 (chunk-major for global_load_lds) + c2n = -0.5*||c||^2 ----
// 16B unit n = ch*2048 + u*128 + cw  holds center (ch*128+cw), k in [u*8, u*8+8).
__global__ __launch_bounds__(256) void pack_kernel(const float* __restrict__ centers,
                                                   _Float16* __restrict__ wh,
                                                   float* __restrict__ c2n) {
    int tid = blockIdx.x * 256 + threadIdx.x;   // 0 .. K*16-1
    int ch = tid >> 11;
    int u  = (tid >> 7) & 15;
    int cw = tid & 127;
    int center = ch * CHUNK_C + cw;
    const float* src = centers + (size_t)center * D + u * 8;
    float4 a = *(const float4*)src;
    float4 b = *(const float4*)(src + 4);
    float f[8] = {a.x, a.y, a.z, a.w, b.x, b.y, b.z, b.w};
    half8 h;
#pragma unroll
    for (int j = 0; j < 8; ++j) h[j] = (_Float16)f[j];
    *(half8*)(wh + (size_t)tid * 8) = h;

    if (blockIdx.x < K / KC) {
        int c_local = threadIdx.x >> 2, part = threadIdx.x & 3;
        int c = blockIdx.x * 64 + c_local;
        const float4* p = (const float4*)(centers + (size_t)c * D + part * 32);
        float s = 0.f;
#pragma unroll
        for (int i = 0; i < 8; ++i) {
            float4 v = p[i];
            s = fmaf(v.x, v.x, s); s = fmaf(v.y, v.y, s);
            s = fmaf(v.z, v.z, s); s = fmaf(v.w, v.w, s);
        }
        s += __shfl_xor(s, 1, 64);
        s += __shfl_xor(s, 2, 64);
        if (part == 0) c2n[c] = -0.5f * s;
    }
}

// ---- single-pass distance kernel: 128 rows/block, full K per block ----
// R11 champion (verified 173.6 us total, dist ~113 us): 256 blocks x 1024
// threads (16 waves = 4 row-quarters x 4 center-quarters), 1 block/CU, dbuf
// LDS + 1 barrier/chunk, packed best-2 screening (epoch in low mantissa),
// exact fp32 refine of 8 candidates/row, fused output writes.
__global__ __launch_bounds__(1024, 4) void dist_kernel(
    const float* __restrict__ x, const float* __restrict__ centers,
    const _Float16* __restrict__ wh, const float* __restrict__ c2n,
    float* __restrict__ out) {
    __shared__ char lds[65536];   // two 32 KB chunk buffers; aliased in epilogue

    const int t    = threadIdx.x;
    const int w    = t >> 6;      // wave 0..15
    const int L    = t & 63;
    const int quad = L >> 4;
    const int n16  = L & 15;
    const int cq   = w & 3;       // center quarter of chunk (32 centers)
    const int rq   = w >> 2;      // row quarter 0..3 (32 rows each)
    const int gr0  = blockIdx.x * ROWS_PER_BLOCK;

    // ---- preload A fragments (this wave's 32 rows, all 128 k, fp16) ----
    half8 Ah[2][4];
#pragma unroll
    for (int rt = 0; rt < 2; ++rt) {
        int r = gr0 + rq * 32 + rt * 16 + n16;
        const float* xr = x + (size_t)r * D + quad * 8;
#pragma unroll
        for (int ks = 0; ks < 4; ++ks) {
            float4 a = *(const float4*)(xr + ks * 32);
            float4 b = *(const float4*)(xr + ks * 32 + 4);
            float f[8] = {a.x, a.y, a.z, a.w, b.x, b.y, b.z, b.w};
            half8 h;
#pragma unroll
            for (int j = 0; j < 8; ++j) h[j] = (_Float16)f[j];
            Ah[rt][ks] = h;
        }
    }

    // packed best-2 per slot k = rt*4+reg (value | 7-bit epoch in low mantissa)
    float b1[8], b2[8];
#pragma unroll
    for (int k = 0; k < 8; ++k) { b1[k] = -1e30f; b2[k] = -1e30f; }

    const char* gh = (const char*)wh;

    // prologue: stage chunk 0 into buf0 (2 async16 per thread: 1024*2*16B = 32 KB)
#pragma unroll
    for (int i = 0; i < 2; ++i) {
        int seg = w * 2 + i;                           // wave-uniform, 0..31
        async_lds16(gh + seg * 1024 + L * 16, lds + seg * 1024);
    }

    // prologue: c2v for chunk 0 (2 center columns of 16 per wave)
    float c2vA[2], c2vB[2];
#pragma unroll
    for (int ct = 0; ct < 2; ++ct) c2vA[ct] = c2n[cq * 32 + ct * 16 + n16];
    __syncthreads();

    for (int ci = 0; ci < NCHUNKS; ++ci) {
        const char* cur = lds + (ci & 1) * 32768;
        // prefetch next chunk (no wait — lands during compute below)
        if (ci + 1 < NCHUNKS) {
            const char* gn = gh + (size_t)(ci + 1) * 32768;
            char* nxt = lds + ((ci + 1) & 1) * 32768;
#pragma unroll
            for (int i = 0; i < 2; ++i) {
                int seg = w * 2 + i;
                async_lds16(gn + seg * 1024 + L * 16, nxt + seg * 1024);
            }
            const int kb1 = (ci + 1) * CHUNK_C + cq * 32;
#pragma unroll
            for (int ct = 0; ct < 2; ++ct) c2vB[ct] = c2n[kb1 + ct * 16 + n16];
        }

        floatx4 acc[2][2];
#pragma unroll
        for (int rt = 0; rt < 2; ++rt)
#pragma unroll
            for (int ct = 0; ct < 2; ++ct)
                acc[rt][ct] = (floatx4){c2vA[ct], c2vA[ct], c2vA[ct], c2vA[ct]};

        __builtin_amdgcn_s_setprio(1);
#pragma unroll
        for (int ks = 0; ks < 4; ++ks) {
            const half8* pb = (const half8*)cur + (ks * 4 + quad) * 128 + cq * 32 + n16;
#pragma unroll
            for (int ct = 0; ct < 2; ++ct) {
                half8 Bf = pb[ct * 16];
                acc[0][ct] = __builtin_amdgcn_mfma_f32_16x16x32_f16(Ah[0][ks], Bf, acc[0][ct], 0, 0, 0);
                acc[1][ct] = __builtin_amdgcn_mfma_f32_16x16x32_f16(Ah[1][ks], Bf, acc[1][ct], 0, 0, 0);
            }
        }
        __builtin_amdgcn_s_setprio(0);

        // pack epoch into low 7 mantissa bits, reduce ct, packed best-2 insert
        const unsigned pk0 = (unsigned)(2 * ci);       // wave-uniform epochs
        const unsigned pk1 = (unsigned)(2 * ci + 1);
#pragma unroll
        for (int rt = 0; rt < 2; ++rt)
#pragma unroll
            for (int reg = 0; reg < 4; ++reg) {
                int k = rt * 4 + reg;
                float v0 = __uint_as_float((__float_as_uint(acc[rt][0][reg]) & ~127u) | pk0);
                float v1 = __uint_as_float((__float_as_uint(acc[rt][1][reg]) & ~127u) | pk1);
                float v  = fmaxf(v0, v1);
                b2[k] = __builtin_amdgcn_fmed3f(b1[k], b2[k], v);  // exact 2nd-max
                b1[k] = fmaxf(b1[k], v);
            }

        // rotate c2v double-buffer
#pragma unroll
        for (int ct = 0; ct < 2; ++ct) c2vA[ct] = c2vB[ct];

        __syncthreads();   // prefetch drained (free) + all waves done reading cur
    }

    int* candL = (int*)lds;       // [128 rows][8 candidates] — buffers are dead now

    // decode epochs -> full center indices, then merge sorted best-2 (max)
    // across all 16 n16 lanes -> best-2 per (row, cq)
#pragma unroll
    for (int k = 0; k < 8; ++k) {
        unsigned u1 = __float_as_uint(b1[k]), u2 = __float_as_uint(b2[k]);
        int e1 = (int)(u1 & 127u), e2 = (int)(u2 & 127u);
        int p1 = (e1 >> 1) * 128 + cq * 32 + (e1 & 1) * 16 + n16;
        int p2 = (e2 >> 1) * 128 + cq * 32 + (e2 & 1) * 16 + n16;
        float v1 = b1[k], v2 = b2[k];
#pragma unroll
        for (int m = 1; m < 16; m <<= 1) {
            float o1 = __shfl_xor(v1, m, 64), o2 = __shfl_xor(v2, m, 64);
            int   q1 = __shfl_xor(p1, m, 64), q2 = __shfl_xor(p2, m, 64);
            bool firstMine = (v1 > o1) || (v1 == o1 && p1 < q1);
            float nv1 = firstMine ? v1 : o1;  int np1 = firstMine ? p1 : q1;
            float cb  = firstMine ? o1 : v1;  int cpi = firstMine ? q1 : p1;  // loser of firsts
            float ob  = firstMine ? v2 : o2;  int obi = firstMine ? p2 : q2;  // winner's own 2nd
            bool secOwn = (ob > cb) || (ob == cb && obi < cpi);
            v1 = nv1; p1 = np1;
            v2 = secOwn ? ob : cb;  p2 = secOwn ? obi : cpi;
        }
        if (n16 == 0) {
            int rloc = rq * 32 + (k >> 2) * 16 + quad * 4 + (k & 3);
            candL[rloc * 8 + cq * 2 + 0] = p1;
            candL[rloc * 8 + cq * 2 + 1] = p2;
        }
    }
    __syncthreads();

    // exact fp32 refine: 8 candidates/row, 1 per thread (128 rows x 8 threads)
    // then write ALL outputs directly (quantized, cluster, min-dist, class)
    {
        int r = t >> 3, p = t & 7;
        int row = gr0 + r;
        int ix = candL[r * 8 + p];
        const float4* xr4 = (const float4*)(x + (size_t)row * D);
        const float4* c4  = (const float4*)(centers + (size_t)ix * D);
        float dot = 0.f, x2s = 0.f, c2 = 0.f;
#pragma unroll
        for (int d4 = 0; d4 < 32; ++d4) {
            float4 xv = xr4[d4], cv = c4[d4];
            dot = fmaf(xv.x, cv.x, dot); dot = fmaf(xv.y, cv.y, dot);
            dot = fmaf(xv.z, cv.z, dot); dot = fmaf(xv.w, cv.w, dot);
            x2s = fmaf(xv.x, xv.x, x2s); x2s = fmaf(xv.y, xv.y, x2s);
            x2s = fmaf(xv.z, xv.z, x2s); x2s = fmaf(xv.w, xv.w, x2s);
            c2  = fmaf(cv.x, cv.x, c2);  c2  = fmaf(cv.y, cv.y, c2);
            c2  = fmaf(cv.z, cv.z, c2);  c2  = fmaf(cv.w, cv.w, c2);
        }
        float sq = x2s + c2 - 2.f * dot;
        // butterfly min-reduce with lowest-index tie-break: all 8 lanes converge
#pragma unroll
        for (int m = 1; m < 8; m <<= 1) {
            float osq = __shfl_xor(sq, m, 64);
            int   oix = __shfl_xor(ix, m, 64);
            if (osq < sq || (osq == sq && oix < ix)) { sq = osq; ix = oix; }
        }

        float* out_clu = out + (size_t)BATCH * D;
        float* out_md  = out_clu + BATCH;
        float* out_cls = out_md + BATCH;
        if (p == 0) {
            out_md[row]  = sqrtf(fmaxf(sq, 0.f));
            out_clu[row] = (float)(ix & (KC - 1));
            out_cls[row] = (float)(ix >> 6);
        }

        // quantized = x + (c - x), elementwise in fp32 (matches reference exactly)
        const float4* cv4 = (const float4*)(centers + (size_t)ix * D) + p * 4;
        const float4* xv4 = (const float4*)(x + (size_t)row * D) + p * 4;
        float4* o4 = (float4*)(out + (size_t)row * D) + p * 4;
#pragma unroll
        for (int i = 0; i < 4; ++i) {
            float4 cv = cv4[i], xv = xv4[i];
            float4 o;
            o.x = xv.x + (cv.x - xv.x);
            o.y = xv.y + (cv.y - xv.y);
            o.z = xv.z + (cv.z - xv.z);
            o.w = xv.w + (cv.w - xv.w);
            o4[i] = o;
        }
    }
}

extern "C" void kernel_launch(void* const* d_in, const int* in_sizes, int n_in,
                              void* d_out, int out_size, void* d_ws, size_t ws_size,
                              hipStream_t stream) {
    const float* x       = (const float*)d_in[0];
    const float* centers = (const float*)d_in[1];
    // d_in[2] = labels (int64) — unused by the forward computation
    float* out = (float*)d_out;

    _Float16* wh  = (_Float16*)d_ws;                  // K*D halves, chunk-major
    float*    c2n = (float*)(wh + (size_t)K * D);     // K floats

    pack_kernel<<<(K * 16) / 256, 256, 0, stream>>>(centers, wh, c2n);
    dist_kernel<<<BATCH / ROWS_PER_BLOCK, 1024, 0, stream>>>(x, centers, wh, c2n, out);
}